// Round 1
// baseline (1397.171 us; speedup 1.0000x reference)
//
#include <hip/hip_runtime.h>

// Problem constants
#define B_SZ 512
#define T_SZ 512
#define I_SZ 256
#define H_SZ 250

typedef __bf16 bf16x8 __attribute__((ext_vector_type(8)));
typedef __bf16 bf16x4 __attribute__((ext_vector_type(4)));
typedef float  f32x4  __attribute__((ext_vector_type(4)));

__device__ __forceinline__ float fast_tanh(float x) {
    float ax = __builtin_fabsf(x);
    float e  = __expf(-2.0f * ax);          // v_exp_f32 path
    float r  = (1.0f - e) / (1.0f + e);
    return __builtin_copysignf(r, x);
}

// ---------------------------------------------------------------------------
// Kernel 1: xproj[b][t][j] = x[b][t][:] . Wx[j][:] + bh[j]   (written to out)
// M = B*T = 262144 rows, K = 256, N = 250 (padded to 256, 2 N-tiles of 128).
// 128x128 tile per block, 256 threads / 4 waves, bf16 MFMA 16x16x32.
// ---------------------------------------------------------------------------
#define BM 128
#define BN 128
#define BK 32
#define LDT 40   // LDS row stride in bf16 elems (80B, 16B-aligned, conflict-safe)

__global__ __launch_bounds__(256, 2) void xproj_kernel(
    const float* __restrict__ x,    // [M][256]
    const float* __restrict__ Wx,   // [250][256]
    const float* __restrict__ bh,   // [250]
    float* __restrict__ out)        // [M][250]
{
    __shared__ __align__(16) __bf16 As[BM * LDT];
    __shared__ __align__(16) __bf16 Bs[BM * LDT];

    const int bm = blockIdx.x >> 1;
    const int bn = blockIdx.x & 1;
    const int m0 = bm * BM;
    const int n0 = bn * BN;

    const int tid  = threadIdx.x;
    const int lane = tid & 63;
    const int wave = tid >> 6;
    const int wm   = wave >> 1;      // wave row (0/1) -> 64 rows
    const int wn   = wave & 1;       // wave col (0/1) -> 64 cols
    const int l15  = lane & 15;
    const int quad = lane >> 4;

    f32x4 acc[4][4];
#pragma unroll
    for (int i = 0; i < 4; ++i)
#pragma unroll
        for (int j = 0; j < 4; ++j)
            acc[i][j] = (f32x4){0.f, 0.f, 0.f, 0.f};

    for (int kk = 0; kk < I_SZ / BK; ++kk) {
        __syncthreads();   // previous iter's frag reads done
        // stage A (x) and B (Wx) tiles: 128 rows x 32 k, fp32 -> bf16
#pragma unroll
        for (int i = 0; i < 4; ++i) {
            int f   = tid + i * 256;        // float4 index 0..1023
            int row = f >> 3;
            int c4  = f & 7;
            // A
            {
                const float4 v = *(const float4*)&x[(size_t)(m0 + row) * I_SZ + kk * BK + c4 * 4];
                bf16x4 b;
                b[0] = (__bf16)v.x; b[1] = (__bf16)v.y; b[2] = (__bf16)v.z; b[3] = (__bf16)v.w;
                *(bf16x4*)&As[row * LDT + c4 * 4] = b;
            }
            // B (guard rows >= 250)
            {
                int gr = n0 + row;
                bf16x4 b;
                if (gr < H_SZ) {
                    const float4 v = *(const float4*)&Wx[(size_t)gr * I_SZ + kk * BK + c4 * 4];
                    b[0] = (__bf16)v.x; b[1] = (__bf16)v.y; b[2] = (__bf16)v.z; b[3] = (__bf16)v.w;
                } else {
                    b[0] = (__bf16)0.f; b[1] = (__bf16)0.f; b[2] = (__bf16)0.f; b[3] = (__bf16)0.f;
                }
                *(bf16x4*)&Bs[row * LDT + c4 * 4] = b;
            }
        }
        __syncthreads();

        bf16x8 af[4], bfr[4];
#pragma unroll
        for (int tm = 0; tm < 4; ++tm)
            af[tm] = *(const bf16x8*)&As[(wm * 64 + tm * 16 + l15) * LDT + quad * 8];
#pragma unroll
        for (int tn = 0; tn < 4; ++tn)
            bfr[tn] = *(const bf16x8*)&Bs[(wn * 64 + tn * 16 + l15) * LDT + quad * 8];
#pragma unroll
        for (int tm = 0; tm < 4; ++tm)
#pragma unroll
            for (int tn = 0; tn < 4; ++tn)
                acc[tm][tn] = __builtin_amdgcn_mfma_f32_16x16x32_bf16(af[tm], bfr[tn], acc[tm][tn], 0, 0, 0);
    }

    // epilogue: C row = quad*4+reg (m), col = lane&15 (n); add bias
#pragma unroll
    for (int tn = 0; tn < 4; ++tn) {
        int gn = n0 + wn * 64 + tn * 16 + l15;
        if (gn >= H_SZ) continue;
        float bias = bh[gn];
#pragma unroll
        for (int tm = 0; tm < 4; ++tm) {
#pragma unroll
            for (int r = 0; r < 4; ++r) {
                int gm = m0 + wm * 64 + tm * 16 + quad * 4 + r;
                out[(size_t)gm * H_SZ + gn] = acc[tm][tn][r] + bias;
            }
        }
    }
}

// ---------------------------------------------------------------------------
// Kernel 2: recurrence. 256 blocks, each owns batch rows {2b, 2b+1}.
// Wh held in registers as bf16 MFMA B-fragments (4 n-tiles x 8 k-tiles/wave).
// h state ping-pong in LDS (16 rows x 264 stride, rows 0/1 live, rest zero).
// Reads xproj from out[b][t][:] and overwrites in place with tanh state.
// ---------------------------------------------------------------------------
#define HLD 264   // LDS row stride for h (bf16): breaks bank conflicts, 16B-mult

__global__ __launch_bounds__(256, 1) void rnn_kernel(
    const float* __restrict__ h0,   // [B][250]
    const float* __restrict__ Wh,   // [250][250]
    float* __restrict__ out)        // [B][T][250], pre-filled with xproj+bias
{
    __shared__ __align__(16) __bf16 hbuf[2][16 * HLD];

    const int b0   = blockIdx.x * 2;
    const int tid  = threadIdx.x;
    const int lane = tid & 63;
    const int wave = tid >> 6;
    const int l15  = lane & 15;
    const int quad = lane >> 4;
    const int j0w  = wave * 64;

    // zero both h buffers (rows 2..15 and cols >=250 must stay 0 forever)
    for (int i = tid; i < 2 * 16 * HLD; i += 256)
        ((__bf16*)hbuf)[i] = (__bf16)0.f;
    __syncthreads();

    // init h rows 0,1 of buffer 0
    for (int k = tid; k < H_SZ; k += 256) {
        hbuf[0][0 * HLD + k] = (__bf16)h0[(size_t)(b0 + 0) * H_SZ + k];
        hbuf[0][1 * HLD + k] = (__bf16)h0[(size_t)(b0 + 1) * H_SZ + k];
    }

    // load Wh fragments into registers: wf[tl][kt], B-frag layout
    // B[n = lane&15][k = quad*8 + e], n = j0w + tl*16 + l15, k = kt*32 + quad*8 + e
    bf16x8 wf[4][8];
#pragma unroll
    for (int tl = 0; tl < 4; ++tl) {
        int j = j0w + tl * 16 + l15;
#pragma unroll
        for (int kt = 0; kt < 8; ++kt) {
            int kb = kt * 32 + quad * 8;
            bf16x8 v;
#pragma unroll
            for (int e = 0; e < 8; ++e) {
                int k = kb + e;
                v[e] = (j < H_SZ && k < H_SZ) ? (__bf16)Wh[(size_t)j * H_SZ + k] : (__bf16)0.f;
            }
            wf[tl][kt] = v;
        }
    }
    __syncthreads();

    for (int t = 0; t < T_SZ; ++t) {
        const int cur = t & 1;
        const int nxt = cur ^ 1;
        __syncthreads();   // hbuf[cur] fully written by previous step

        // A-fragments: A[m = lane&15][k = quad*8 + e] from h rows (m=batch 0/1)
        bf16x8 af[8];
#pragma unroll
        for (int kt = 0; kt < 8; ++kt)
            af[kt] = *(const bf16x8*)&hbuf[cur][l15 * HLD + kt * 32 + quad * 8];

        // prefetch xproj for this step (valid on quad 0 lanes only)
        float xp0[4], xp1[4];
#pragma unroll
        for (int tl = 0; tl < 4; ++tl) {
            int j = j0w + tl * 16 + l15;
            bool v = (quad == 0) && (j < H_SZ);
            size_t o0 = ((size_t)(b0 + 0) * T_SZ + t) * H_SZ + j;
            size_t o1 = ((size_t)(b0 + 1) * T_SZ + t) * H_SZ + j;
            xp0[tl] = v ? out[o0] : 0.f;
            xp1[tl] = v ? out[o1] : 0.f;
        }

#pragma unroll
        for (int tl = 0; tl < 4; ++tl) {
            f32x4 acc = (f32x4){0.f, 0.f, 0.f, 0.f};
#pragma unroll
            for (int kt = 0; kt < 8; ++kt)
                acc = __builtin_amdgcn_mfma_f32_16x16x32_bf16(af[kt], wf[tl][kt], acc, 0, 0, 0);

            // C layout: row(m=batch) = quad*4 + reg, col(n=j) = lane&15
            int j = j0w + tl * 16 + l15;
            if (quad == 0 && j < H_SZ) {
                float v0 = fast_tanh(acc[0] + xp0[tl]);
                float v1 = fast_tanh(acc[1] + xp1[tl]);
                out[((size_t)(b0 + 0) * T_SZ + t) * H_SZ + j] = v0;
                out[((size_t)(b0 + 1) * T_SZ + t) * H_SZ + j] = v1;
                hbuf[nxt][0 * HLD + j] = (__bf16)v0;
                hbuf[nxt][1 * HLD + j] = (__bf16)v1;
            }
        }
    }
}

extern "C" void kernel_launch(void* const* d_in, const int* in_sizes, int n_in,
                              void* d_out, int out_size, void* d_ws, size_t ws_size,
                              hipStream_t stream) {
    const float* x  = (const float*)d_in[0];
    const float* h  = (const float*)d_in[1];
    const float* Wx = (const float*)d_in[2];
    const float* Wh = (const float*)d_in[3];
    const float* bh = (const float*)d_in[4];
    float* out = (float*)d_out;

    const int M = B_SZ * T_SZ;                 // 262144
    xproj_kernel<<<dim3((M / BM) * 2), dim3(256), 0, stream>>>(x, Wx, bh, out);
    rnn_kernel<<<dim3(B_SZ / 2), dim3(256), 0, stream>>>(h, Wh, out);
}